// Round 1
// baseline (256.401 us; speedup 1.0000x reference)
//
#include <hip/hip_runtime.h>
#include <math.h>

#define BATCH 64
#define MEM 1024
#define SENT 16
#define NEMBD 128
#define HID 40
#define HOPS 3
#define NANS 20
#define NEGV -1000000000.0f

// ---------------- Kernel A: ek[b][m][h] ----------------
// one wave per (b,m) task; 4 waves / 256-thread block.
__global__ __launch_bounds__(256) void ek_kernel(
    const int* __restrict__ story, const float* __restrict__ emb,
    const float* __restrict__ A_w, const float* __restrict__ pe,
    float* __restrict__ ek) {
  __shared__ float pe_s[SENT * NEMBD];   // 8 KB
  __shared__ float Aw_s[HID * NEMBD];    // 20 KB
  for (int i = threadIdx.x; i < SENT * NEMBD; i += 256) pe_s[i] = pe[i];
  for (int i = threadIdx.x; i < HID * NEMBD; i += 256) Aw_s[i] = A_w[i];
  __syncthreads();

  const int wid = threadIdx.x >> 6;
  const int lane = threadIdx.x & 63;
  const int task = (blockIdx.x << 2) | wid;     // 0 .. 65535  (= b*MEM + m)

  const int* st = story + (size_t)task * SENT;
  int myidx = (lane < SENT) ? st[lane] : 0;

  float s0 = 0.f, s1 = 0.f;
#pragma unroll
  for (int s = 0; s < SENT; ++s) {
    int idx = __shfl(myidx, s);
    const float* row = emb + (size_t)idx * NEMBD;
    s0 = fmaf(pe_s[s * NEMBD + lane],       row[lane],      s0);
    s1 = fmaf(pe_s[s * NEMBD + 64 + lane],  row[64 + lane], s1);
  }

  // project by A_w: ek[h] = sum_e summed[e]*A_w[h][e]; butterfly reduce per h
  float myout = 0.f;
#pragma unroll
  for (int h = 0; h < HID; ++h) {
    float p = s0 * Aw_s[h * NEMBD + lane] + s1 * Aw_s[h * NEMBD + 64 + lane];
#pragma unroll
    for (int off = 32; off; off >>= 1) p += __shfl_xor(p, off);
    if (lane == h) myout = p;
  }
  if (lane < HID) ek[(size_t)task * HID + lane] = myout;
}

// ---------------- Kernel B: hops + logits + log_softmax ----------------
// one 1024-thread block per batch element; thread t owns memory slot m=t.
__global__ __launch_bounds__(1024) void hops_kernel(
    const int* __restrict__ story, const int* __restrict__ question,
    const float* __restrict__ emb, const float* __restrict__ A_w,
    const float* __restrict__ Rs, const float* __restrict__ Wd,
    const float* __restrict__ bd, const float* __restrict__ pe,
    const float* __restrict__ ek, float* __restrict__ out) {
  const int b = blockIdx.x;
  const int t = threadIdx.x;
  const int wid = t >> 6;
  const int lane = t & 63;

  __shared__ float q_s[HID];
  __shared__ float o_s[HID];
  __shared__ float tmp_s[HID];           // HID >= NANS
  __shared__ float summed[NEMBD];
  __shared__ int   qidx[SENT];
  __shared__ float wpart[16][HID];
  __shared__ float red_s[16];
  __shared__ float bcast;

  // cache my ek row (reused across all 3 attends)
  float row[HID];
  const float* ekp = ek + ((size_t)b * MEM + t) * HID;
#pragma unroll
  for (int i = 0; i < HID / 4; ++i) {
    float4 v = reinterpret_cast<const float4*>(ekp)[i];
    row[4 * i] = v.x; row[4 * i + 1] = v.y; row[4 * i + 2] = v.z; row[4 * i + 3] = v.w;
  }
  const bool masked = (story[((size_t)b * MEM + t) * SENT] == 0);

  // ---- eq = (sum_s table[question[b,s]] * pe[s]) @ A_w.T ----
  if (t < SENT) qidx[t] = question[b * SENT + t];
  __syncthreads();
  if (t < NEMBD) {
    float acc = 0.f;
    for (int s = 0; s < SENT; ++s)
      acc = fmaf(emb[(size_t)qidx[s] * NEMBD + t], pe[s * NEMBD + t], acc);
    summed[t] = acc;
  }
  __syncthreads();
  if (t < HID) {
    float acc = 0.f;
    for (int e = 0; e < NEMBD; ++e) acc = fmaf(summed[e], A_w[t * NEMBD + e], acc);
    q_s[t] = acc;
  }
  __syncthreads();

  for (int hop = 0; hop < HOPS; ++hop) {
    // ---- attend: scores ----
    float sc = 0.f;
#pragma unroll
    for (int h = 0; h < HID; ++h) sc = fmaf(q_s[h], row[h], sc);
    if (masked) sc = NEGV;

    // block max
    float mx = sc;
#pragma unroll
    for (int off = 32; off; off >>= 1) mx = fmaxf(mx, __shfl_xor(mx, off));
    if (lane == 0) red_s[wid] = mx;
    __syncthreads();
    if (t == 0) {
      float m2 = red_s[0];
      for (int i = 1; i < 16; ++i) m2 = fmaxf(m2, red_s[i]);
      bcast = m2;
    }
    __syncthreads();
    mx = bcast;

    float ex = __expf(sc - mx);
    float sm = ex;
#pragma unroll
    for (int off = 32; off; off >>= 1) sm += __shfl_xor(sm, off);
    if (lane == 0) red_s[wid] = sm;
    __syncthreads();
    if (t == 0) {
      float s2 = 0.f;
      for (int i = 0; i < 16; ++i) s2 += red_s[i];
      bcast = s2;
    }
    __syncthreads();
    float attn = ex / bcast;

    // ---- o[h] = sum_m attn[m] * ek[m][h] ----
    float myo = 0.f;
#pragma unroll
    for (int h = 0; h < HID; ++h) {
      float p = attn * row[h];
#pragma unroll
      for (int off = 32; off; off >>= 1) p += __shfl_xor(p, off);
      if (lane == h) myo = p;
    }
    if (lane < HID) wpart[wid][lane] = myo;
    __syncthreads();
    if (t < HID) {
      float acc = 0.f;
      for (int w = 0; w < 16; ++w) acc += wpart[w][t];
      o_s[t] = acc;
    }
    __syncthreads();

    // ---- q = (q + o) @ Rs[hop].T ----
    if (t < HID) {
      float acc = 0.f;
      const float* R = Rs + (size_t)hop * HID * HID + (size_t)t * HID;
      for (int k = 0; k < HID; ++k) acc = fmaf(q_s[k] + o_s[k], R[k], acc);
      tmp_s[t] = acc;
    }
    __syncthreads();
    if (t < HID) q_s[t] = tmp_s[t];
    __syncthreads();
  }

  // ---- logits = q @ Wd.T + bd ; out = log_softmax ----
  if (t < NANS) {
    float acc = bd[t];
    for (int k = 0; k < HID; ++k) acc = fmaf(q_s[k], Wd[t * HID + k], acc);
    tmp_s[t] = acc;
  }
  __syncthreads();
  if (t == 0) {
    float m2 = tmp_s[0];
    for (int i = 1; i < NANS; ++i) m2 = fmaxf(m2, tmp_s[i]);
    float s2 = 0.f;
    for (int i = 0; i < NANS; ++i) s2 += __expf(tmp_s[i] - m2);
    bcast = m2 + __logf(s2);
  }
  __syncthreads();
  if (t < NANS) out[b * NANS + t] = tmp_s[t] - bcast;
}

extern "C" void kernel_launch(void* const* d_in, const int* in_sizes, int n_in,
                              void* d_out, int out_size, void* d_ws, size_t ws_size,
                              hipStream_t stream) {
  const int*   story    = (const int*)d_in[0];
  const int*   question = (const int*)d_in[1];
  // d_in[2] = all_answers (unused: enc_ans is dead code in the reference)
  const float* emb      = (const float*)d_in[3];
  const float* A_w      = (const float*)d_in[4];
  // d_in[5] = B_w (unused)
  const float* Rs       = (const float*)d_in[6];
  const float* Wd       = (const float*)d_in[7];
  const float* bd       = (const float*)d_in[8];
  const float* pe       = (const float*)d_in[9];
  float* out = (float*)d_out;
  float* ek  = (float*)d_ws;   // BATCH*MEM*HID floats = 10.49 MB

  ek_kernel<<<(BATCH * MEM) / 4, 256, 0, stream>>>(story, emb, A_w, pe, ek);
  hops_kernel<<<BATCH, 1024, 0, stream>>>(story, question, emb, A_w, Rs, Wd, bd, pe,
                                          ek, out);
}

// Round 2
// 114.658 us; speedup vs baseline: 2.2362x; 2.2362x over previous
//
#include <hip/hip_runtime.h>
#include <math.h>

#define BATCH 64
#define MEM 1024
#define SENT 16
#define NEMBD 128
#define HID 40
#define HOPS 3
#define NANS 20
#define VOCAB 32000
#define NEGV -1000000000.0f

// ---------------- Kernel 0: PQ[v][80] = [emb@A_w^T | (emb*gamma)@A_w^T] ----------------
// pe[s,e] = alpha_s + beta_s*gamma_e (rank-2), so the pe-weighted sum + A_w projection
// collapses to per-token gathers of P,Q rows. 64-row tile, 256 thr, 4v x 5c microtile.
__global__ __launch_bounds__(256) void pq_kernel(
    const float* __restrict__ emb, const float* __restrict__ A_w,
    float* __restrict__ PQ) {
  __shared__ float embS[64][132];   // +4 pad: float4-aligned, bank-spread
  __shared__ float Ws[128][80];
  const int t = threadIdx.x;
  const int vbase = blockIdx.x * 64;

  for (int i = t; i < 64 * 32; i += 256) {
    int r = i >> 5, c4 = i & 31;
    float4 v = reinterpret_cast<const float4*>(emb + (size_t)(vbase + r) * NEMBD)[c4];
    *reinterpret_cast<float4*>(&embS[r][c4 * 4]) = v;
  }
  for (int i = t; i < 128 * 80; i += 256) {
    int e = i / 80, c = i % 80;
    float w = A_w[(c % 40) * NEMBD + e];
    if (c >= 40) w *= (float)(e + 1) * (1.0f / 128.0f);   // gamma_e
    Ws[e][c] = w;
  }
  __syncthreads();

  const int tx = t & 15, ty = t >> 4;
  float acc[4][5] = {};
#pragma unroll 4
  for (int e = 0; e < 128; ++e) {
    float a0 = embS[ty * 4 + 0][e];
    float a1 = embS[ty * 4 + 1][e];
    float a2 = embS[ty * 4 + 2][e];
    float a3 = embS[ty * 4 + 3][e];
    float b[5];
#pragma unroll
    for (int k = 0; k < 5; ++k) b[k] = Ws[e][tx + 16 * k];
#pragma unroll
    for (int k = 0; k < 5; ++k) {
      acc[0][k] = fmaf(a0, b[k], acc[0][k]);
      acc[1][k] = fmaf(a1, b[k], acc[1][k]);
      acc[2][k] = fmaf(a2, b[k], acc[2][k]);
      acc[3][k] = fmaf(a3, b[k], acc[3][k]);
    }
  }
#pragma unroll
  for (int j = 0; j < 4; ++j)
#pragma unroll
    for (int k = 0; k < 5; ++k)
      PQ[(size_t)(vbase + ty * 4 + j) * 80 + tx + 16 * k] = acc[j][k];
}

// ---------------- Kernel A: ek[task][h] = sum_s a_s*P[idx_s,h] + b_s*Q[idx_s,h] ------
// 2 tasks per wave (32 lanes each), 8 tasks per 256-thread block. 2.5 KB LDS.
__global__ __launch_bounds__(256) void gather_kernel(
    const int* __restrict__ story, const float* __restrict__ PQ,
    float* __restrict__ ek) {
  __shared__ float accum[8][80];
  const int t = threadIdx.x;
  const int wid = t >> 6, lane = t & 63;
  const int sub = lane & 31;
  const int tl = wid * 2 + (lane >> 5);        // 0..7
  const int task = blockIdx.x * 8 + tl;        // = b*MEM + m

  int myidx = 0;
  if (sub < SENT) myidx = story[(size_t)task * SENT + sub];

  float acc0 = 0.f, acc1 = 0.f, acc2 = 0.f;
#pragma unroll
  for (int s = 0; s < SENT; ++s) {
    int idx = __shfl(myidx, (lane & 32) + s);
    const float* p = PQ + (size_t)idx * 80;
    float al = 1.0f - (float)(s + 1) * 0.0625f;
    float be = (float)(s + 1) * 0.125f - 1.0f;
    acc0 = fmaf(al, p[sub], acc0);                       // f = sub      (P)
    float w1 = (sub < 8) ? al : be;                      // f = 32+sub   (P if <40)
    acc1 = fmaf(w1, p[32 + sub], acc1);
    if (sub < 16) acc2 = fmaf(be, p[64 + sub], acc2);    // f = 64+sub   (Q)
  }
  accum[tl][sub] = acc0;
  accum[tl][32 + sub] = acc1;
  if (sub < 16) accum[tl][64 + sub] = acc2;
  __syncthreads();

  const int base = blockIdx.x * 8;
  for (int i = t; i < 8 * HID; i += 256) {
    int tl2 = i / HID, h = i % HID;
    ek[(size_t)(base + tl2) * HID + h] = accum[tl2][h] + accum[tl2][40 + h];
  }
}

// ---------------- Kernel B: hops + logits + log_softmax ----------------
__global__ __launch_bounds__(1024) void hops_kernel(
    const int* __restrict__ story, const int* __restrict__ question,
    const float* __restrict__ PQ, const float* __restrict__ Rs,
    const float* __restrict__ Wd, const float* __restrict__ bd,
    const float* __restrict__ ek, float* __restrict__ out) {
  const int b = blockIdx.x;
  const int t = threadIdx.x;
  const int wid = t >> 6;
  const int lane = t & 63;

  __shared__ float q_s[HID];
  __shared__ float o_s[HID];
  __shared__ float tmp_s[HID];
  __shared__ int   qidx[SENT];
  __shared__ float wpart[16][HID];
  __shared__ float red_s[16];
  __shared__ float bcast;

  float row[HID];
  const float* ekp = ek + ((size_t)b * MEM + t) * HID;
#pragma unroll
  for (int i = 0; i < HID / 4; ++i) {
    float4 v = reinterpret_cast<const float4*>(ekp)[i];
    row[4 * i] = v.x; row[4 * i + 1] = v.y; row[4 * i + 2] = v.z; row[4 * i + 3] = v.w;
  }
  const bool masked = (story[((size_t)b * MEM + t) * SENT] == 0);

  // ---- eq via PQ gather ----
  if (t < SENT) qidx[t] = question[b * SENT + t];
  __syncthreads();
  if (t < HID) {
    float acc = 0.f;
    for (int s = 0; s < SENT; ++s) {
      const float* p = PQ + (size_t)qidx[s] * 80;
      float al = 1.0f - (float)(s + 1) * 0.0625f;
      float be = (float)(s + 1) * 0.125f - 1.0f;
      acc = fmaf(al, p[t], acc);
      acc = fmaf(be, p[40 + t], acc);
    }
    q_s[t] = acc;
  }
  __syncthreads();

  for (int hop = 0; hop < HOPS; ++hop) {
    float sc = 0.f;
#pragma unroll
    for (int h = 0; h < HID; ++h) sc = fmaf(q_s[h], row[h], sc);
    if (masked) sc = NEGV;

    float mx = sc;
#pragma unroll
    for (int off = 32; off; off >>= 1) mx = fmaxf(mx, __shfl_xor(mx, off));
    if (lane == 0) red_s[wid] = mx;
    __syncthreads();
    if (t == 0) {
      float m2 = red_s[0];
      for (int i = 1; i < 16; ++i) m2 = fmaxf(m2, red_s[i]);
      bcast = m2;
    }
    __syncthreads();
    mx = bcast;

    float ex = __expf(sc - mx);
    float sm = ex;
#pragma unroll
    for (int off = 32; off; off >>= 1) sm += __shfl_xor(sm, off);
    if (lane == 0) red_s[wid] = sm;
    __syncthreads();
    if (t == 0) {
      float s2 = 0.f;
      for (int i = 0; i < 16; ++i) s2 += red_s[i];
      bcast = s2;
    }
    __syncthreads();
    float attn = ex / bcast;

    float myo = 0.f;
#pragma unroll
    for (int h = 0; h < HID; ++h) {
      float p = attn * row[h];
#pragma unroll
      for (int off = 32; off; off >>= 1) p += __shfl_xor(p, off);
      if (lane == h) myo = p;
    }
    if (lane < HID) wpart[wid][lane] = myo;
    __syncthreads();
    if (t < HID) {
      float acc = 0.f;
      for (int w = 0; w < 16; ++w) acc += wpart[w][t];
      o_s[t] = acc;
    }
    __syncthreads();

    if (t < HID) {
      float acc = 0.f;
      const float* R = Rs + (size_t)hop * HID * HID + (size_t)t * HID;
      for (int k = 0; k < HID; ++k) acc = fmaf(q_s[k] + o_s[k], R[k], acc);
      tmp_s[t] = acc;
    }
    __syncthreads();
    if (t < HID) q_s[t] = tmp_s[t];
    __syncthreads();
  }

  if (t < NANS) {
    float acc = bd[t];
    for (int k = 0; k < HID; ++k) acc = fmaf(q_s[k], Wd[t * HID + k], acc);
    tmp_s[t] = acc;
  }
  __syncthreads();
  if (t == 0) {
    float m2 = tmp_s[0];
    for (int i = 1; i < NANS; ++i) m2 = fmaxf(m2, tmp_s[i]);
    float s2 = 0.f;
    for (int i = 0; i < NANS; ++i) s2 += __expf(tmp_s[i] - m2);
    bcast = m2 + __logf(s2);
  }
  __syncthreads();
  if (t < NANS) out[b * NANS + t] = tmp_s[t] - bcast;
}

extern "C" void kernel_launch(void* const* d_in, const int* in_sizes, int n_in,
                              void* d_out, int out_size, void* d_ws, size_t ws_size,
                              hipStream_t stream) {
  const int*   story    = (const int*)d_in[0];
  const int*   question = (const int*)d_in[1];
  const float* emb      = (const float*)d_in[3];
  const float* A_w      = (const float*)d_in[4];
  const float* Rs       = (const float*)d_in[6];
  const float* Wd       = (const float*)d_in[7];
  const float* bd       = (const float*)d_in[8];
  float* out = (float*)d_out;

  float* PQ = (float*)d_ws;                         // 32000*80*4 = 10.24 MB
  float* ek = PQ + (size_t)VOCAB * 80;              // 64*1024*40*4 = 10.49 MB

  pq_kernel<<<VOCAB / 64, 256, 0, stream>>>(emb, A_w, PQ);
  gather_kernel<<<(BATCH * MEM) / 8, 256, 0, stream>>>(story, PQ, ek);
  hops_kernel<<<BATCH, 1024, 0, stream>>>(story, question, PQ, Rs, Wd, bd, ek, out);
}

// Round 3
// 68.525 us; speedup vs baseline: 3.7417x; 1.6732x over previous
//
#include <hip/hip_runtime.h>
#include <math.h>

#define BATCH 64
#define MEM 1024
#define SENT 16
#define NEMBD 128
#define HID 40
#define HOPS 3
#define NANS 20
#define VOCAB 32000

typedef unsigned int uint;
typedef unsigned short ushort;

__device__ __forceinline__ float blo(uint u){ union{uint i;float f;}c; c.i = u<<16; return c.f; }
__device__ __forceinline__ float bhi(uint u){ union{uint i;float f;}c; c.i = u & 0xffff0000u; return c.f; }
__device__ __forceinline__ uint pkbf(float a, float b){
  union{float f;uint i;}ca, cb; ca.f = a; cb.f = b;
  uint ra = (ca.i + 0x7fffu + ((ca.i>>16)&1u)) >> 16;      // RNE f32->bf16
  uint rb = (cb.i + 0x7fffu + ((cb.i>>16)&1u)) & 0xffff0000u;
  return rb | ra;
}

// ---------------- Kernel 0: PQb[v][40] = bf16 pairs of [emb@A^T | (emb*gamma)@A^T] ----
__global__ __launch_bounds__(256) void pq_kernel(
    const float* __restrict__ emb, const float* __restrict__ A_w,
    uint* __restrict__ PQb) {
  __shared__ float embS[64][132];
  __shared__ float Wst[80][132];
  const int t = threadIdx.x;
  const int vbase = blockIdx.x * 64;

  for (int i = t; i < 64 * 32; i += 256) {
    int r = i >> 5, c4 = i & 31;
    float4 v = reinterpret_cast<const float4*>(emb + (size_t)(vbase + r) * NEMBD)[c4];
    *reinterpret_cast<float4*>(&embS[r][c4 * 4]) = v;
  }
  for (int i = t; i < 80 * 128; i += 256) {
    int c = i >> 7, e = i & 127;
    int h = (c < 40) ? c : (c - 40);
    float w = A_w[h * NEMBD + e];
    if (c >= 40) w *= (float)(e + 1) * (1.0f / 128.0f);   // gamma_e
    Wst[c][e] = w;
  }
  __syncthreads();

  const int tx = t & 7, ty = t >> 3;      // tx: col-group of 10, ty: row-pair
  float acc[2][10] = {};
#pragma unroll 2
  for (int e4 = 0; e4 < 32; ++e4) {
    float4 a0 = *reinterpret_cast<const float4*>(&embS[2 * ty][e4 * 4]);
    float4 a1 = *reinterpret_cast<const float4*>(&embS[2 * ty + 1][e4 * 4]);
#pragma unroll
    for (int cc = 0; cc < 10; ++cc) {
      float4 w = *reinterpret_cast<const float4*>(&Wst[tx * 10 + cc][e4 * 4]);
      acc[0][cc] += a0.x * w.x + a0.y * w.y + a0.z * w.z + a0.w * w.w;
      acc[1][cc] += a1.x * w.x + a1.y * w.y + a1.z * w.z + a1.w * w.w;
    }
  }
#pragma unroll
  for (int rr = 0; rr < 2; ++rr) {
    int r = vbase + 2 * ty + rr;
#pragma unroll
    for (int p = 0; p < 5; ++p)
      PQb[(size_t)r * 40 + tx * 5 + p] = pkbf(acc[rr][2 * p], acc[rr][2 * p + 1]);
  }
}

// ---------------- Kernel A: ekT2[b][hp][m] = bf16 pair (h=2hp,2hp+1) ----------------
__global__ __launch_bounds__(256) void gather_kernel(
    const int* __restrict__ story, const uint* __restrict__ PQb,
    uint* __restrict__ ekT2) {
  __shared__ float accS[8][80];
  const int t = threadIdx.x;
  const int wid = t >> 6, lane = t & 63;
  const int sub = lane & 31;
  const int tl = wid * 2 + (lane >> 5);        // 0..7
  const int task = blockIdx.x * 8 + tl;        // = b*MEM + m

  int myidx = 0;
  if (sub < SENT) myidx = story[(size_t)task * SENT + sub];

  float a0 = 0.f, a1 = 0.f, a2 = 0.f, a3 = 0.f;
#pragma unroll
  for (int s = 0; s < SENT; ++s) {
    int idx = __shfl(myidx, (lane & 32) + s);
    const uint* p = PQb + (size_t)idx * 40;
    float al = 1.0f - (float)(s + 1) * 0.0625f;
    float be = (float)(s + 1) * 0.125f - 1.0f;
    uint u = p[sub];                            // pair f=(2sub,2sub+1)
    float w = (sub < 20) ? al : be;             // f<40 -> P weight, else Q
    a0 = fmaf(w, blo(u), a0);
    a1 = fmaf(w, bhi(u), a1);
    if (sub < 8) {                              // pair f=(64+2sub,65+2sub), Q
      uint u2 = p[32 + sub];
      a2 = fmaf(be, blo(u2), a2);
      a3 = fmaf(be, bhi(u2), a3);
    }
  }
  accS[tl][2 * sub] = a0;
  accS[tl][2 * sub + 1] = a1;
  if (sub < 8) { accS[tl][64 + 2 * sub] = a2; accS[tl][65 + 2 * sub] = a3; }
  __syncthreads();

  if (t < 160) {
    int hp = t >> 3, j = t & 7;
    int b = (blockIdx.x * 8) >> 10;
    int m = (blockIdx.x * 8 + j) & 1023;
    float v0 = accS[j][2 * hp]     + accS[j][40 + 2 * hp];   // P+Q -> ek[h]
    float v1 = accS[j][2 * hp + 1] + accS[j][41 + 2 * hp];
    ekT2[((size_t)b * 20 + hp) * 1024 + m] = pkbf(v0, v1);
  }
}

// ---------------- Kernel B: hops + logits + log_softmax (ekT in LDS, no shuffles) ----
__global__ __launch_bounds__(1024) void hops_kernel(
    const int* __restrict__ story, const int* __restrict__ question,
    const uint* __restrict__ PQb, const uint* __restrict__ ekT2,
    const float* __restrict__ Rs, const float* __restrict__ Wd,
    const float* __restrict__ bd, float* __restrict__ out) {
  __shared__ uint  ekS[20][1024];         // 80 KB bf16 pairs
  __shared__ float attnS[1024];           // raw exp(sc)
  __shared__ float wpart[32][42];
  __shared__ float RsS[HOPS * HID * HID];
  __shared__ float WdS[NANS * HID];
  __shared__ float bdS[NANS];
  __shared__ float qS[2][HID];
  __shared__ float oqS[HID];
  __shared__ float wsum[16];
  __shared__ float invS;
  __shared__ float lseS;
  __shared__ int   qidxS[SENT];

  const int b = blockIdx.x;
  const int t = threadIdx.x;
  const int wid = t >> 6, lane = t & 63;

  // ---- prologue: stage ekT (80 KB), weights, question ----
  {
    const uint* src = ekT2 + (size_t)b * 20 * 1024;
#pragma unroll
    for (int j = 0; j < 5; ++j) {
      uint4 v = reinterpret_cast<const uint4*>(src)[j * 1024 + t];
      *reinterpret_cast<uint4*>(&ekS[0][0] + 4 * (j * 1024 + t)) = v;
    }
  }
  for (int i = t; i < HOPS * HID * HID; i += 1024) RsS[i] = Rs[i];
  for (int i = t; i < NANS * HID; i += 1024) WdS[i] = Wd[i];
  if (t < NANS) bdS[t] = bd[t];
  if (t < SENT) qidxS[t] = question[b * SENT + t];
  const bool masked = (story[((size_t)b * MEM + t) * SENT] == 0);
  __syncthreads();

  // ---- eq from PQb ----
  if (t < HID) {
    int hp = t >> 1, sel = t & 1;
    float acc = 0.f;
    for (int s = 0; s < SENT; ++s) {
      const uint* p = PQb + (size_t)qidxS[s] * 40;
      uint u1 = p[hp], u2 = p[20 + hp];
      float vP = sel ? bhi(u1) : blo(u1);
      float vQ = sel ? bhi(u2) : blo(u2);
      float al = 1.0f - (float)(s + 1) * 0.0625f;
      float be = (float)(s + 1) * 0.125f - 1.0f;
      acc = fmaf(al, vP, acc);
      acc = fmaf(be, vQ, acc);
    }
    qS[0][t] = acc;
  }
  __syncthreads();

  int cur = 0;
  for (int hop = 0; hop < HOPS; ++hop) {
    // scores: sc[m=t] = q . ek[m]  (no max-subtract: |sc| << 80 by construction)
    float sc = 0.f;
#pragma unroll
    for (int hp = 0; hp < 20; ++hp) {
      uint u = ekS[hp][t];
      sc = fmaf(qS[cur][2 * hp],     blo(u), sc);
      sc = fmaf(qS[cur][2 * hp + 1], bhi(u), sc);
    }
    float ex = masked ? 0.f : __expf(sc);
    attnS[t] = ex;
    float sm = ex;
#pragma unroll
    for (int off = 32; off; off >>= 1) sm += __shfl_xor(sm, off);
    if (lane == 0) wsum[wid] = sm;
    __syncthreads();                                  // bar A

    if (t < 640) {                                    // o partials, LDS-transpose
      int hp = t >> 5, c = t & 31;
      float o0 = 0.f, o1 = 0.f;
#pragma unroll 8
      for (int j = 0; j < 32; ++j) {
        int m = c + (j << 5);                         // conflict-free: bank = c
        float a = attnS[m];
        uint u = ekS[hp][m];
        o0 = fmaf(a, blo(u), o0);
        o1 = fmaf(a, bhi(u), o1);
      }
      wpart[c][2 * hp]     = o0;
      wpart[c][2 * hp + 1] = o1;
    } else if (t == 1023) {
      float tot = 0.f;
#pragma unroll
      for (int i = 0; i < 16; ++i) tot += wsum[i];
      invS = 1.0f / tot;
    }
    __syncthreads();                                  // bar B

    if (t < HID) {                                    // combine + add q
      float s2 = 0.f;
#pragma unroll 8
      for (int c = 0; c < 32; ++c) s2 += wpart[c][t];
      oqS[t] = qS[cur][t] + invS * s2;
    }
    __syncthreads();                                  // bar C

    if (t < HID) {                                    // q' = (q+o) @ R^T
      const float* R = &RsS[hop * HID * HID + t * HID];
      float acc = 0.f;
#pragma unroll 8
      for (int k = 0; k < HID; ++k) acc = fmaf(oqS[k], R[k], acc);
      qS[cur ^ 1][t] = acc;
    }
    __syncthreads();                                  // bar D
    cur ^= 1;
  }

  // ---- logits + log_softmax ----
  if (t < NANS) {
    float acc = bdS[t];
#pragma unroll 8
    for (int k = 0; k < HID; ++k) acc = fmaf(qS[cur][k], WdS[t * HID + k], acc);
    attnS[t] = acc;
  }
  __syncthreads();
  if (t == 0) {
    float mx = attnS[0];
    for (int i = 1; i < NANS; ++i) mx = fmaxf(mx, attnS[i]);
    float s2 = 0.f;
    for (int i = 0; i < NANS; ++i) s2 += __expf(attnS[i] - mx);
    lseS = mx + __logf(s2);
  }
  __syncthreads();
  if (t < NANS) out[b * NANS + t] = attnS[t] - lseS;
}

extern "C" void kernel_launch(void* const* d_in, const int* in_sizes, int n_in,
                              void* d_out, int out_size, void* d_ws, size_t ws_size,
                              hipStream_t stream) {
  const int*   story    = (const int*)d_in[0];
  const int*   question = (const int*)d_in[1];
  const float* emb      = (const float*)d_in[3];
  const float* A_w      = (const float*)d_in[4];
  const float* Rs       = (const float*)d_in[6];
  const float* Wd       = (const float*)d_in[7];
  const float* bd       = (const float*)d_in[8];
  float* out = (float*)d_out;

  uint* PQb  = (uint*)d_ws;                       // 32000*40*4 = 5.12 MB
  uint* ekT2 = PQb + (size_t)VOCAB * 40;          // 64*20*1024*4 = 5.24 MB

  pq_kernel<<<VOCAB / 64, 256, 0, stream>>>(emb, A_w, PQb);
  gather_kernel<<<(BATCH * MEM) / 8, 256, 0, stream>>>(story, PQb, ekT2);
  hops_kernel<<<BATCH, 1024, 0, stream>>>(story, question, PQb, ekT2, Rs, Wd, bd, out);
}

// Round 4
// 61.325 us; speedup vs baseline: 4.1810x; 1.1174x over previous
//
#include <hip/hip_runtime.h>
#include <math.h>

#define BATCH 64
#define MEM 1024
#define SENT 16
#define NEMBD 128
#define HID 40
#define HOPS 3
#define NANS 20
#define VOCAB 32000

typedef unsigned int uint;

__device__ __forceinline__ float blo(uint u){ union{uint i;float f;}c; c.i = u<<16; return c.f; }
__device__ __forceinline__ float bhi(uint u){ union{uint i;float f;}c; c.i = u & 0xffff0000u; return c.f; }
__device__ __forceinline__ uint pkbf(float a, float b){
  union{float f;uint i;}ca, cb; ca.f = a; cb.f = b;
  uint ra = (ca.i + 0x7fffu + ((ca.i>>16)&1u)) >> 16;      // RNE f32->bf16
  uint rb = (cb.i + 0x7fffu + ((cb.i>>16)&1u)) & 0xffff0000u;
  return rb | ra;
}

// ---- Kernel 0: PQb[v][40] interleaved bf16 pairs: slot 2j = P-pair j, 2j+1 = Q-pair j
// P = emb@A^T, Q = (emb*gamma)@A^T  (pe[s,e] = alpha_s + beta_s*gamma_e is rank-2).
__global__ __launch_bounds__(256) void pq_kernel(
    const float* __restrict__ emb, const float* __restrict__ A_w,
    uint* __restrict__ PQb) {
  __shared__ float embS[64][132];
  __shared__ float Wst[80][132];
  const int t = threadIdx.x;
  const int vbase = blockIdx.x * 64;

  for (int i = t; i < 64 * 32; i += 256) {
    int r = i >> 5, c4 = i & 31;
    float4 v = reinterpret_cast<const float4*>(emb + (size_t)(vbase + r) * NEMBD)[c4];
    *reinterpret_cast<float4*>(&embS[r][c4 * 4]) = v;
  }
  for (int i = t; i < 80 * 128; i += 256) {
    int c = i >> 7, e = i & 127;
    int h = (c < 40) ? c : (c - 40);
    float w = A_w[h * NEMBD + e];
    if (c >= 40) w *= (float)(e + 1) * (1.0f / 128.0f);   // gamma_e
    Wst[c][e] = w;
  }
  __syncthreads();

  const int tx = t & 7, ty = t >> 3;      // tx: col-group of 10 (tx<4 => P, else Q)
  float acc[2][10] = {};
#pragma unroll 2
  for (int e4 = 0; e4 < 32; ++e4) {
    float4 a0 = *reinterpret_cast<const float4*>(&embS[2 * ty][e4 * 4]);
    float4 a1 = *reinterpret_cast<const float4*>(&embS[2 * ty + 1][e4 * 4]);
#pragma unroll
    for (int cc = 0; cc < 10; ++cc) {
      float4 w = *reinterpret_cast<const float4*>(&Wst[tx * 10 + cc][e4 * 4]);
      acc[0][cc] += a0.x * w.x + a0.y * w.y + a0.z * w.z + a0.w * w.w;
      acc[1][cc] += a1.x * w.x + a1.y * w.y + a1.z * w.z + a1.w * w.w;
    }
  }
#pragma unroll
  for (int rr = 0; rr < 2; ++rr) {
    int r = vbase + 2 * ty + rr;
#pragma unroll
    for (int p = 0; p < 5; ++p) {
      uint packed = pkbf(acc[rr][2 * p], acc[rr][2 * p + 1]);
      int slot = (tx < 4) ? 2 * (5 * tx + p)                 // P pair j=5tx+p
                          : 2 * (5 * (tx - 4) + p) + 1;      // Q pair j=5(tx-4)+p
      PQb[(size_t)r * 40 + slot] = packed;
    }
  }
}

// ---- Kernel A: ekT2[b][hp][m] = bf16 pair (ek[2hp], ek[2hp+1]); no LDS, no sync ----
// 2 tasks per wave (32-lane halves); lane sub<20 owns output pair hp=sub.
__global__ __launch_bounds__(256) void gather_kernel(
    const int* __restrict__ story, const uint* __restrict__ PQb,
    uint* __restrict__ ekT2) {
  const int t = threadIdx.x;
  const int wid = t >> 6, lane = t & 63;
  const int sub = lane & 31;
  const int tl = wid * 2 + (lane >> 5);        // 0..7
  const int task = blockIdx.x * 8 + tl;        // = b*MEM + m

  int midx = (sub < SENT) ? story[(size_t)task * SENT + sub] : 0;
  const int off = (sub < 20) ? 2 * sub : 0;    // clamp: lanes 20-31 dup-load pair 0

  float a0 = 0.f, a1 = 0.f;
#pragma unroll
  for (int s = 0; s < SENT; ++s) {
    int idx = __shfl(midx, (lane & 32) + s);
    uint2 u = *reinterpret_cast<const uint2*>(PQb + (size_t)idx * 40 + off);
    float al = 1.0f - (float)(s + 1) * 0.0625f;
    float be = (float)(s + 1) * 0.125f - 1.0f;
    a0 = fmaf(al, blo(u.x), a0);   // P contribution
    a0 = fmaf(be, blo(u.y), a0);   // Q contribution
    a1 = fmaf(al, bhi(u.x), a1);
    a1 = fmaf(be, bhi(u.y), a1);
  }
  if (sub < 20) {
    int b = task >> 10, m = task & 1023;
    ekT2[((size_t)b * 20 + sub) * 1024 + m] = pkbf(a0, a1);
  }
}

// ---- Kernel B: hops + logits + log_softmax (ekT in LDS, shuffle-free o-reduce) ----
__global__ __launch_bounds__(1024) void hops_kernel(
    const int* __restrict__ story, const int* __restrict__ question,
    const uint* __restrict__ PQb, const uint* __restrict__ ekT2,
    const float* __restrict__ Rs, const float* __restrict__ Wd,
    const float* __restrict__ bd, float* __restrict__ out) {
  __shared__ uint  ekS[20][1024];         // 80 KB bf16 pairs
  __shared__ float attnS[1024];           // raw exp(sc)
  __shared__ float wpart[32][42];
  __shared__ float RsS[HOPS * HID * HID];
  __shared__ float WdS[NANS * HID];
  __shared__ float bdS[NANS];
  __shared__ float qS[2][HID];
  __shared__ float oqS[HID];
  __shared__ float wsum[16];
  __shared__ float invS;
  __shared__ float lseS;
  __shared__ int   qidxS[SENT];

  const int b = blockIdx.x;
  const int t = threadIdx.x;
  const int wid = t >> 6, lane = t & 63;

  {
    const uint* src = ekT2 + (size_t)b * 20 * 1024;
#pragma unroll
    for (int j = 0; j < 5; ++j) {
      uint4 v = reinterpret_cast<const uint4*>(src)[j * 1024 + t];
      *reinterpret_cast<uint4*>(&ekS[0][0] + 4 * (j * 1024 + t)) = v;
    }
  }
  for (int i = t; i < HOPS * HID * HID; i += 1024) RsS[i] = Rs[i];
  for (int i = t; i < NANS * HID; i += 1024) WdS[i] = Wd[i];
  if (t < NANS) bdS[t] = bd[t];
  if (t < SENT) qidxS[t] = question[b * SENT + t];
  const bool masked = (story[((size_t)b * MEM + t) * SENT] == 0);
  __syncthreads();

  // ---- eq from PQb (interleaved layout) ----
  if (t < HID) {
    int j = t >> 1, sel = t & 1;
    float acc = 0.f;
    for (int s = 0; s < SENT; ++s) {
      const uint* p = PQb + (size_t)qidxS[s] * 40;
      uint uP = p[2 * j], uQ = p[2 * j + 1];
      float vP = sel ? bhi(uP) : blo(uP);
      float vQ = sel ? bhi(uQ) : blo(uQ);
      float al = 1.0f - (float)(s + 1) * 0.0625f;
      float be = (float)(s + 1) * 0.125f - 1.0f;
      acc = fmaf(al, vP, acc);
      acc = fmaf(be, vQ, acc);
    }
    qS[0][t] = acc;
  }
  __syncthreads();

  int cur = 0;
  for (int hop = 0; hop < HOPS; ++hop) {
    float sc = 0.f;
#pragma unroll
    for (int hp = 0; hp < 20; ++hp) {
      uint u = ekS[hp][t];
      sc = fmaf(qS[cur][2 * hp],     blo(u), sc);
      sc = fmaf(qS[cur][2 * hp + 1], bhi(u), sc);
    }
    float ex = masked ? 0.f : __expf(sc);   // |sc| small by construction; no max-sub
    attnS[t] = ex;
    float sm = ex;
#pragma unroll
    for (int off = 32; off; off >>= 1) sm += __shfl_xor(sm, off);
    if (lane == 0) wsum[wid] = sm;
    __syncthreads();                                  // bar A

    if (t < 640) {                                    // o partials, LDS-transpose
      int hp = t >> 5, c = t & 31;
      float o0 = 0.f, o1 = 0.f;
#pragma unroll 8
      for (int j = 0; j < 32; ++j) {
        int m = c + (j << 5);                         // conflict-free: bank = c
        float a = attnS[m];
        uint u = ekS[hp][m];
        o0 = fmaf(a, blo(u), o0);
        o1 = fmaf(a, bhi(u), o1);
      }
      wpart[c][2 * hp]     = o0;
      wpart[c][2 * hp + 1] = o1;
    } else if (t == 1023) {
      float tot = 0.f;
#pragma unroll
      for (int i = 0; i < 16; ++i) tot += wsum[i];
      invS = 1.0f / tot;
    }
    __syncthreads();                                  // bar B

    if (t < HID) {
      float s2 = 0.f;
#pragma unroll 8
      for (int c = 0; c < 32; ++c) s2 += wpart[c][t];
      oqS[t] = qS[cur][t] + invS * s2;
    }
    __syncthreads();                                  // bar C

    if (t < HID) {
      const float* R = &RsS[hop * HID * HID + t * HID];
      float acc = 0.f;
#pragma unroll 8
      for (int k = 0; k < HID; ++k) acc = fmaf(oqS[k], R[k], acc);
      qS[cur ^ 1][t] = acc;
    }
    __syncthreads();                                  // bar D
    cur ^= 1;
  }

  if (t < NANS) {
    float acc = bdS[t];
#pragma unroll 8
    for (int k = 0; k < HID; ++k) acc = fmaf(qS[cur][k], WdS[t * HID + k], acc);
    attnS[t] = acc;
  }
  __syncthreads();
  if (t == 0) {
    float mx = attnS[0];
    for (int i = 1; i < NANS; ++i) mx = fmaxf(mx, attnS[i]);
    float s2 = 0.f;
    for (int i = 0; i < NANS; ++i) s2 += __expf(attnS[i] - mx);
    lseS = mx + __logf(s2);
  }
  __syncthreads();
  if (t < NANS) out[b * NANS + t] = attnS[t] - lseS;
}

extern "C" void kernel_launch(void* const* d_in, const int* in_sizes, int n_in,
                              void* d_out, int out_size, void* d_ws, size_t ws_size,
                              hipStream_t stream) {
  const int*   story    = (const int*)d_in[0];
  const int*   question = (const int*)d_in[1];
  const float* emb      = (const float*)d_in[3];
  const float* A_w      = (const float*)d_in[4];
  const float* Rs       = (const float*)d_in[6];
  const float* Wd       = (const float*)d_in[7];
  const float* bd       = (const float*)d_in[8];
  float* out = (float*)d_out;

  uint* PQb  = (uint*)d_ws;                       // 32000*40*4 = 5.12 MB
  uint* ekT2 = PQb + (size_t)VOCAB * 40;          // 64*20*1024*4 = 5.24 MB

  pq_kernel<<<VOCAB / 64, 256, 0, stream>>>(emb, A_w, PQb);
  gather_kernel<<<(BATCH * MEM) / 8, 256, 0, stream>>>(story, PQb, ekT2);
  hops_kernel<<<BATCH, 1024, 0, stream>>>(story, question, PQb, ekT2, Rs, Wd, bd, out);
}

// Round 5
// 54.302 us; speedup vs baseline: 4.7218x; 1.1293x over previous
//
#include <hip/hip_runtime.h>
#include <math.h>

#define BATCH 64
#define MEM 1024
#define SENT 16
#define NEMBD 128
#define HID 40
#define HOPS 3
#define NANS 20
#define VOCAB 32000

typedef unsigned int uint;
typedef __attribute__((ext_vector_type(8))) short short8;
typedef __attribute__((ext_vector_type(4))) float f32x4;

__device__ __forceinline__ float blo(uint u){ union{uint i;float f;}c; c.i = u<<16; return c.f; }
__device__ __forceinline__ float bhi(uint u){ union{uint i;float f;}c; c.i = u & 0xffff0000u; return c.f; }
__device__ __forceinline__ unsigned short bfr(float x){
  union{float f;uint i;}c; c.f = x;
  return (unsigned short)((c.i + 0x7fffu + ((c.i>>16)&1u)) >> 16);   // RNE f32->bf16
}
__device__ __forceinline__ uint pkbf(float a, float b){
  union{float f;uint i;}ca, cb; ca.f = a; cb.f = b;
  uint ra = (ca.i + 0x7fffu + ((ca.i>>16)&1u)) >> 16;
  uint rb = (cb.i + 0x7fffu + ((cb.i>>16)&1u)) & 0xffff0000u;
  return rb | ra;
}

// ---- Kernel 0 (MFMA): PQb[v][40] interleaved bf16 pairs ----
// Halfword stream p=0..79 per row: p -> h = 2*(p>>2)+(p&1), Q iff (p>>1)&1.
// C = emb[32000x128] @ W[128x80], W[e][p] = A_w[h(p)][e] * (Q ? (e+1)/128 : 1).
// K-loading uses the same (g,j)->k placement for A and B, so the MFMA dot
// product is correct regardless of the HW's per-lane k-order (bijection arg).
__global__ __launch_bounds__(256) void pq_kernel(
    const float* __restrict__ emb, const float* __restrict__ A_w,
    uint* __restrict__ PQb) {
  __shared__ float CmS[64][81];
  const int t = threadIdx.x;
  const int w = t >> 6, l = t & 63;
  const int g = l >> 4, n16 = l & 15;
  const int vbase = blockIdx.x * 64;
  const int row = vbase + w * 16 + n16;

  // B fragments (block-invariant): 5 N-tiles x 4 K-steps
  short8 bfrag[5][4];
#pragma unroll
  for (int nt = 0; nt < 5; ++nt) {
    int pc = nt * 16 + n16;
    int h = 2 * (pc >> 2) + (pc & 1);
    bool isQ = (pc >> 1) & 1;
    const float* wr = A_w + h * NEMBD;
#pragma unroll
    for (int ks = 0; ks < 4; ++ks) {
      int kb = ks * 32 + 8 * g;
      float4 v0 = *reinterpret_cast<const float4*>(wr + kb);
      float4 v1 = *reinterpret_cast<const float4*>(wr + kb + 4);
      float vv[8] = {v0.x, v0.y, v0.z, v0.w, v1.x, v1.y, v1.z, v1.w};
      short8 s;
#pragma unroll
      for (int j = 0; j < 8; ++j) {
        float x = vv[j];
        if (isQ) x *= (float)(kb + j + 1) * (1.0f / 128.0f);   // gamma_e
        s[j] = (short)bfr(x);
      }
      bfrag[nt][ks] = s;
    }
  }

  f32x4 acc[5] = {};
  const float* er = emb + (size_t)row * NEMBD;
#pragma unroll
  for (int ks = 0; ks < 4; ++ks) {
    int kb = ks * 32 + 8 * g;
    float4 v0 = *reinterpret_cast<const float4*>(er + kb);
    float4 v1 = *reinterpret_cast<const float4*>(er + kb + 4);
    float vv[8] = {v0.x, v0.y, v0.z, v0.w, v1.x, v1.y, v1.z, v1.w};
    short8 a;
#pragma unroll
    for (int j = 0; j < 8; ++j) a[j] = (short)bfr(vv[j]);
#pragma unroll
    for (int nt = 0; nt < 5; ++nt)
      acc[nt] = __builtin_amdgcn_mfma_f32_16x16x32_bf16(a, bfrag[nt][ks], acc[nt], 0, 0, 0);
  }

  // C/D layout (verified): lane l reg r -> row 4*(l>>4)+r, col l&15
#pragma unroll
  for (int nt = 0; nt < 5; ++nt)
#pragma unroll
    for (int r = 0; r < 4; ++r)
      CmS[w * 16 + 4 * g + r][nt * 16 + n16] = acc[nt][r];
  __syncthreads();

#pragma unroll
  for (int it = 0; it < 10; ++it) {
    int i = it * 256 + t;                 // 64 rows x 40 uints
    int rr = i / 40, u = i % 40;
    PQb[(size_t)(vbase + rr) * 40 + u] = pkbf(CmS[rr][2 * u], CmS[rr][2 * u + 1]);
  }
}

// ---- Kernel A: ekT2[b][hp][m] = bf16 pair (ek[2hp], ek[2hp+1]); no LDS, no sync ----
__global__ __launch_bounds__(256) void gather_kernel(
    const int* __restrict__ story, const uint* __restrict__ PQb,
    uint* __restrict__ ekT2) {
  const int t = threadIdx.x;
  const int wid = t >> 6, lane = t & 63;
  const int sub = lane & 31;
  const int tl = wid * 2 + (lane >> 5);        // 0..7
  const int task = blockIdx.x * 8 + tl;        // = b*MEM + m

  int midx = (sub < SENT) ? story[(size_t)task * SENT + sub] : 0;
  const int off = (sub < 20) ? 2 * sub : 0;    // lanes 20-31 dup-load pair 0 (same line)

  float a0 = 0.f, a1 = 0.f;
#pragma unroll
  for (int s = 0; s < SENT; ++s) {
    int idx = __shfl(midx, (lane & 32) + s);
    uint2 u = *reinterpret_cast<const uint2*>(PQb + (size_t)idx * 40 + off);
    float al = 1.0f - (float)(s + 1) * 0.0625f;
    float be = (float)(s + 1) * 0.125f - 1.0f;
    a0 = fmaf(al, blo(u.x), a0);   // P
    a0 = fmaf(be, blo(u.y), a0);   // Q
    a1 = fmaf(al, bhi(u.x), a1);
    a1 = fmaf(be, bhi(u.y), a1);
  }
  if (sub < 20) {
    int b = task >> 10, m = task & 1023;
    ekT2[((size_t)b * 20 + sub) * 1024 + m] = pkbf(a0, a1);
  }
}

// ---- Kernel B: hops + logits + log_softmax (ekT in LDS, shuffle-free o-reduce) ----
__global__ __launch_bounds__(1024) void hops_kernel(
    const int* __restrict__ story, const int* __restrict__ question,
    const uint* __restrict__ PQb, const uint* __restrict__ ekT2,
    const float* __restrict__ Rs, const float* __restrict__ Wd,
    const float* __restrict__ bd, float* __restrict__ out) {
  __shared__ uint  ekS[20][1024];         // 80 KB bf16 pairs
  __shared__ float attnS[1024];           // raw exp(sc)
  __shared__ float wpart[32][42];
  __shared__ float RsS[HOPS * HID * HID];
  __shared__ float WdS[NANS * HID];
  __shared__ float bdS[NANS];
  __shared__ float qS[2][HID];
  __shared__ float oqS[HID];
  __shared__ float wsum[16];
  __shared__ float invS;
  __shared__ float lseS;
  __shared__ int   qidxS[SENT];

  const int b = blockIdx.x;
  const int t = threadIdx.x;
  const int wid = t >> 6, lane = t & 63;

  {
    const uint* src = ekT2 + (size_t)b * 20 * 1024;
#pragma unroll
    for (int j = 0; j < 5; ++j) {
      uint4 v = reinterpret_cast<const uint4*>(src)[j * 1024 + t];
      *reinterpret_cast<uint4*>(&ekS[0][0] + 4 * (j * 1024 + t)) = v;
    }
  }
  for (int i = t; i < HOPS * HID * HID; i += 1024) RsS[i] = Rs[i];
  for (int i = t; i < NANS * HID; i += 1024) WdS[i] = Wd[i];
  if (t < NANS) bdS[t] = bd[t];
  if (t < SENT) qidxS[t] = question[b * SENT + t];
  const bool masked = (story[((size_t)b * MEM + t) * SENT] == 0);
  __syncthreads();

  // ---- eq from PQb (interleaved layout) ----
  if (t < HID) {
    int j = t >> 1, sel = t & 1;
    float acc = 0.f;
    for (int s = 0; s < SENT; ++s) {
      const uint* p = PQb + (size_t)qidxS[s] * 40;
      uint uP = p[2 * j], uQ = p[2 * j + 1];
      float vP = sel ? bhi(uP) : blo(uP);
      float vQ = sel ? bhi(uQ) : blo(uQ);
      float al = 1.0f - (float)(s + 1) * 0.0625f;
      float be = (float)(s + 1) * 0.125f - 1.0f;
      acc = fmaf(al, vP, acc);
      acc = fmaf(be, vQ, acc);
    }
    qS[0][t] = acc;
  }
  __syncthreads();

  int cur = 0;
  for (int hop = 0; hop < HOPS; ++hop) {
    float sc = 0.f;
#pragma unroll
    for (int hp = 0; hp < 20; ++hp) {
      uint u = ekS[hp][t];
      sc = fmaf(qS[cur][2 * hp],     blo(u), sc);
      sc = fmaf(qS[cur][2 * hp + 1], bhi(u), sc);
    }
    float ex = masked ? 0.f : __expf(sc);   // |sc| small by construction; no max-sub
    attnS[t] = ex;
    float sm = ex;
#pragma unroll
    for (int off = 32; off; off >>= 1) sm += __shfl_xor(sm, off);
    if (lane == 0) wsum[wid] = sm;
    __syncthreads();                                  // bar A

    if (t < 640) {                                    // o partials, LDS-transpose
      int hp = t >> 5, c = t & 31;
      float o0 = 0.f, o1 = 0.f;
#pragma unroll 8
      for (int j = 0; j < 32; ++j) {
        int m = c + (j << 5);                         // conflict-free: bank = c
        float a = attnS[m];
        uint u = ekS[hp][m];
        o0 = fmaf(a, blo(u), o0);
        o1 = fmaf(a, bhi(u), o1);
      }
      wpart[c][2 * hp]     = o0;
      wpart[c][2 * hp + 1] = o1;
    } else if (t == 1023) {
      float tot = 0.f;
#pragma unroll
      for (int i = 0; i < 16; ++i) tot += wsum[i];
      invS = 1.0f / tot;
    }
    __syncthreads();                                  // bar B

    if (t < HID) {
      float s2 = 0.f;
#pragma unroll 8
      for (int c = 0; c < 32; ++c) s2 += wpart[c][t];
      oqS[t] = qS[cur][t] + invS * s2;
    }
    __syncthreads();                                  // bar C

    if (t < HID) {
      const float* R = &RsS[hop * HID * HID + t * HID];
      float acc = 0.f;
#pragma unroll 8
      for (int k = 0; k < HID; ++k) acc = fmaf(oqS[k], R[k], acc);
      qS[cur ^ 1][t] = acc;
    }
    __syncthreads();                                  // bar D
    cur ^= 1;
  }

  if (t < NANS) {
    float acc = bdS[t];
#pragma unroll 8
    for (int k = 0; k < HID; ++k) acc = fmaf(qS[cur][k], WdS[t * HID + k], acc);
    attnS[t] = acc;
  }
  __syncthreads();
  if (t == 0) {
    float mx = attnS[0];
    for (int i = 1; i < NANS; ++i) mx = fmaxf(mx, attnS[i]);
    float s2 = 0.f;
    for (int i = 0; i < NANS; ++i) s2 += __expf(attnS[i] - mx);
    lseS = mx + __logf(s2);
  }
  __syncthreads();
  if (t < NANS) out[b * NANS + t] = attnS[t] - lseS;
}

extern "C" void kernel_launch(void* const* d_in, const int* in_sizes, int n_in,
                              void* d_out, int out_size, void* d_ws, size_t ws_size,
                              hipStream_t stream) {
  const int*   story    = (const int*)d_in[0];
  const int*   question = (const int*)d_in[1];
  const float* emb      = (const float*)d_in[3];
  const float* A_w      = (const float*)d_in[4];
  const float* Rs       = (const float*)d_in[6];
  const float* Wd       = (const float*)d_in[7];
  const float* bd       = (const float*)d_in[8];
  float* out = (float*)d_out;

  uint* PQb  = (uint*)d_ws;                       // 32000*40*4 = 5.12 MB
  uint* ekT2 = PQb + (size_t)VOCAB * 40;          // 64*20*1024*4 = 5.24 MB

  pq_kernel<<<VOCAB / 64, 256, 0, stream>>>(emb, A_w, PQb);
  gather_kernel<<<(BATCH * MEM) / 8, 256, 0, stream>>>(story, PQb, ekT2);
  hops_kernel<<<BATCH, 1024, 0, stream>>>(story, question, PQb, ekT2, Rs, Wd, bd, out);
}